// Round 6
// baseline (466.173 us; speedup 1.0000x reference)
//
#include <hip/hip_runtime.h>
#include <hip/hip_cooperative_groups.h>

namespace cg = cooperative_groups;

#define B_    16
#define NL    21
#define NG    42
#define ZW    64
#define HID   1024
#define IMG   128
#define NOUT  12288   // 3*64*64
#define MROWS 336     // B_*NL
#define MPAD  384
#define CGRID 256     // 1 block/CU: co-residency satisfiable under any occupancy calc

typedef __bf16 bf16x8 __attribute__((ext_vector_type(8)));
typedef float f32x4 __attribute__((ext_vector_type(4)));
typedef unsigned short ushort4v __attribute__((ext_vector_type(4)));

static __device__ __forceinline__ unsigned short f2bf(float f) {
    union { float f; unsigned int u; } v; v.f = f;
    unsigned int r = v.u + 0x7fffu + ((v.u >> 16) & 1u);  // RNE
    return (unsigned short)(r >> 16);
}

// global -> LDS direct copy, 16B per lane (dest must be wave-uniform base + lane*16)
static __device__ __forceinline__ void gload_lds16(const void* g, void* l) {
    __builtin_amdgcn_global_load_lds(
        (const __attribute__((address_space(1))) void*)g,
        (__attribute__((address_space(3))) void*)l,
        16, 0, 0);
}

// ===========================================================================
// Phase bodies, shared by the cooperative kernel and the fallback kernels.
// ===========================================================================

// Phase A: one 64x64 tile of w2 (1024x12288 f32) -> w2t (12288x1024 bf16,
// k-contig, pre-swizzled k ^= (col&7)<<3). task in [0,3072). Needs 16640B smem.
static __device__ __forceinline__ void phaseA_tile(const float* __restrict__ w2,
                                                   unsigned short* __restrict__ w2t,
                                                   int task, int t, char* smem) {
    float (*tile)[65] = reinterpret_cast<float (*)[65]>(smem);
    const int nt = task % 192, kt = task / 192;
    const int n0 = nt * 64,    k0 = kt * 64;
    #pragma unroll
    for (int i = 0; i < 4; ++i) {
        int lin = i * 256 + t;
        int kr  = lin >> 4;
        int nc  = (lin & 15) << 2;
        float4 v = *reinterpret_cast<const float4*>(
            w2 + (size_t)(k0 + kr) * NOUT + n0 + nc);
        tile[kr][nc + 0] = v.x; tile[kr][nc + 1] = v.y;
        tile[kr][nc + 2] = v.z; tile[kr][nc + 3] = v.w;
    }
    __syncthreads();
    #pragma unroll
    for (int i = 0; i < 4; ++i) {
        int lin = i * 256 + t;
        int nc  = lin >> 4;
        int kc  = (lin & 15) << 2;
        ushort4v r;
        r.x = f2bf(tile[kc + 0][nc]);
        r.y = f2bf(tile[kc + 1][nc]);
        r.z = f2bf(tile[kc + 2][nc]);
        r.w = f2bf(tile[kc + 3][nc]);
        int kc_s = kc ^ ((nc & 7) << 3);   // pre-swizzle for phase D ds_read
        *reinterpret_cast<ushort4v*>(
            w2t + (size_t)(n0 + nc) * HID + k0 + kc_s) = r;
    }
    __syncthreads();   // tile reused by next task
}

// Phase B: one row r of h = relu(z_what @ w1 + b1) (bf16, pre-swizzled).
// r in [0,MPAD); rows >= MROWS zero-padded. Needs 256B smem.
static __device__ __forceinline__ void phaseB_row(const float* __restrict__ z_what,
                                                  const float* __restrict__ w1,
                                                  const float* __restrict__ b1,
                                                  unsigned short* __restrict__ h,
                                                  int r, int t, char* smem) {
    const int sw = (r & 7) << 3;
    if (r >= MROWS) {                       // block-uniform branch
        #pragma unroll
        for (int i = 0; i < 4; ++i) {
            int k = t + i * 256;
            h[(size_t)r * HID + ((k & ~63) | ((k & 63) ^ sw))] = 0;
        }
        return;
    }
    float* zs = reinterpret_cast<float*>(smem);
    if (t < ZW) zs[t] = z_what[(size_t)r * ZW + t];
    __syncthreads();
    float acc[4];
    #pragma unroll
    for (int i = 0; i < 4; ++i) acc[i] = b1[t + i * 256];
    for (int k = 0; k < ZW; ++k) {
        float z = zs[k];
        const float* wr = w1 + (size_t)k * HID + t;
        acc[0] = fmaf(z, wr[0],   acc[0]);
        acc[1] = fmaf(z, wr[256], acc[1]);
        acc[2] = fmaf(z, wr[512], acc[2]);
        acc[3] = fmaf(z, wr[768], acc[3]);
    }
    #pragma unroll
    for (int i = 0; i < 4; ++i) {
        int k = t + i * 256;
        h[(size_t)r * HID + ((k & ~63) | ((k & 63) ^ sw))] =
            f2bf(acc[i] > 0.f ? acc[i] : 0.f);
    }
    __syncthreads();                        // zs reused by next task
}

// Phase C: batch b softmax weights + affine params + pixel bbox (wave 0 only).
static __device__ __forceinline__ void phaseC_batch(const float* __restrict__ z_where,
                                                    const float* __restrict__ z_depth,
                                                    const int* __restrict__ z_present,
                                                    const int* __restrict__ indices,
                                                    float* __restrict__ params,
                                                    int b, int t) {
    if (t >= 64) return;
    const bool valid = t < NG;
    int idx  = valid ? indices[t] : 0;
    int pres = valid ? z_present[b * NG + t] : 0;
    float zd = z_depth[b * NL + idx];
    const bool on = valid && (pres == 1);
    float val = on ? zd : -__builtin_inff();
    float m = val;
    #pragma unroll
    for (int off = 32; off; off >>= 1) m = fmaxf(m, __shfl_xor(m, off));
    float e = on ? __expf(val - m) : 0.f;
    float s = e;
    #pragma unroll
    for (int off = 32; off; off >>= 1) s += __shfl_xor(s, off);
    if (valid) {
        float wn = e / s;
        const float* zw = z_where + (size_t)(b * NG + t) * 4;
        float cx = zw[0], cy = zw[1], ww = zw[2], hh = zw[3];
        float wm = fmaxf(ww, 1e-6f), hm = fmaxf(hh, 1e-6f);
        float Ax = 32.f / wm, Ay = 32.f / hm;
        float Bx = 31.5f - (2.f * cx - 1.f) * Ax;
        float By = 31.5f - (2.f * cy - 1.f) * Ay;
        float xlof = ((-1.f - Bx) / Ax + 1.f) * 64.f - 0.5f;
        float xhif = (( 64.f - Bx) / Ax + 1.f) * 64.f - 0.5f;
        float ylof = ((-1.f - By) / Ay + 1.f) * 64.f - 0.5f;
        float yhif = (( 64.f - By) / Ay + 1.f) * 64.f - 0.5f;
        int xlo = max(0,   (int)floorf(xlof));
        int xhi = min(128, (int)floorf(xhif) + 2);
        int ylo = max(0,   (int)floorf(ylof));
        int yhi = min(128, (int)floorf(yhif) + 2);
        float* p = params + (size_t)(b * NG + t) * 16;
        p[0] = wn; p[1] = Ax; p[2] = Bx; p[3] = Ay; p[4] = By;
        p[5] = __int_as_float(b * NL + idx);
        p[6] = __int_as_float(xlo); p[7] = __int_as_float(xhi);
        p[8] = __int_as_float(ylo); p[9] = __int_as_float(yhi);
    }
}

// Phase D: one 128x128 tile of dec = sigmoid(h @ w2t^T + b2).
// task in [0,288): bn = task%96, bm = task/96. Needs 65536B smem.
static __device__ __forceinline__ void phaseD_tile(const unsigned short* __restrict__ h,
                                                   const unsigned short* __restrict__ w2t,
                                                   const float* __restrict__ b2,
                                                   float* __restrict__ dec,
                                                   int task, int t, char* smem) {
    const int bn   = task % 96;
    const int bm   = task / 96;
    const int row0 = bm * 128, col0 = bn * 128;
    const int lane = t & 63, wid = t >> 6;
    const int wr = (wid >> 1) * 64, wc = (wid & 1) * 64;

    f32x4 acc[4][4];
    const f32x4 zero = {0.f, 0.f, 0.f, 0.f};
    #pragma unroll
    for (int m = 0; m < 4; ++m)
        #pragma unroll
        for (int n = 0; n < 4; ++n) acc[m][n] = zero;

    const char* hB = (const char*)h   + ((size_t)row0 << 11);
    const char* wB = (const char*)w2t + ((size_t)col0 << 11);

    #define STAGE(kt_, buf_)                                                    \
        do {                                                                    \
            int kby = (kt_) << 7;                                               \
            char* ldsA = smem + (buf_) * 32768;                                 \
            char* ldsB = ldsA + 16384;                                          \
            _Pragma("unroll")                                                   \
            for (int r_ = 0; r_ < 4; ++r_) {                                    \
                int ci  = r_ * 256 + t;                                         \
                int row = ci >> 3, kc = ci & 7;                                 \
                gload_lds16(hB + ((size_t)row << 11) + kby + (kc << 4),         \
                            ldsA + ci * 16);                                    \
                gload_lds16(wB + ((size_t)row << 11) + kby + (kc << 4),         \
                            ldsB + ci * 16);                                    \
            }                                                                   \
        } while (0)

    #define COMPUTE(buf_)                                                       \
        do {                                                                    \
            const char* Ab = smem + (buf_) * 32768;                             \
            const char* Bb = Ab + 16384;                                        \
            _Pragma("unroll")                                                   \
            for (int ks = 0; ks < 2; ++ks) {                                    \
                int kb = ks * 64 + ((lane >> 4) << 4);                          \
                bf16x8 a[4], bb[4];                                             \
                _Pragma("unroll")                                               \
                for (int m = 0; m < 4; ++m) {                                   \
                    int row = wr + m * 16 + (lane & 15);                        \
                    a[m] = *reinterpret_cast<const bf16x8*>(                    \
                        Ab + row * 128 + (kb ^ ((row & 7) << 4)));              \
                }                                                               \
                _Pragma("unroll")                                               \
                for (int n = 0; n < 4; ++n) {                                   \
                    int col = wc + n * 16 + (lane & 15);                        \
                    bb[n] = *reinterpret_cast<const bf16x8*>(                   \
                        Bb + col * 128 + (kb ^ ((col & 7) << 4)));              \
                }                                                               \
                _Pragma("unroll")                                               \
                for (int m = 0; m < 4; ++m)                                     \
                    _Pragma("unroll")                                           \
                    for (int n = 0; n < 4; ++n)                                 \
                        acc[m][n] = __builtin_amdgcn_mfma_f32_16x16x32_bf16(    \
                            a[m], bb[n], acc[m][n], 0, 0, 0);                   \
            }                                                                   \
        } while (0)

    STAGE(0, 0);
    __syncthreads();
    int cur = 0;
    for (int kt = 1; kt < 16; ++kt) {
        STAGE(kt, cur ^ 1);
        COMPUTE(cur);
        __syncthreads();
        cur ^= 1;
    }
    COMPUTE(cur);
    #undef STAGE
    #undef COMPUTE

    const int rbase = row0 + wr + ((lane >> 4) << 2);
    const int cbase = col0 + wc + (lane & 15);
    #pragma unroll
    for (int n = 0; n < 4; ++n) {
        int col = cbase + n * 16;
        float bias = b2[col];
        #pragma unroll
        for (int m = 0; m < 4; ++m) {
            #pragma unroll
            for (int j = 0; j < 4; ++j) {
                int row = rbase + m * 16 + j;
                float v = acc[m][n][j] + bias;
                dec[(size_t)row * NOUT + col] = 1.f / (1.f + __expf(-v));
            }
        }
    }
    __syncthreads();   // smem reused by next task
}

// Phase E: one 16x16 output tile: glimpse compaction + bilinear + composite.
// task in [0,1024). Needs ~1100B smem.
static __device__ __forceinline__ void phaseE_tile(const float* __restrict__ dec,
                                                   const float* __restrict__ params,
                                                   float* __restrict__ out,
                                                   int task, int t, char* smem) {
    float* Pc    = reinterpret_cast<float*>(smem);              // 42*6 floats
    int*   s_cnt = reinterpret_cast<int*>(smem + NG * 6 * 4);
    const int b    = task >> 6;
    const int tile = task & 63;
    const int tx0 = (tile & 7) << 4, ty0 = (tile >> 3) << 4;
    if (t < 64) {
        bool pass = false;
        float wn = 0.f, Ax = 0.f, Bx = 0.f, Ay = 0.f, By = 0.f, ridx = 0.f;
        if (t < NG) {
            const float* p = params + (size_t)(b * NG + t) * 16;
            wn = p[0];
            if (wn != 0.f) {
                int xlo = __float_as_int(p[6]), xhi = __float_as_int(p[7]);
                int ylo = __float_as_int(p[8]), yhi = __float_as_int(p[9]);
                if (xlo < tx0 + 16 && xhi > tx0 && ylo < ty0 + 16 && yhi > ty0) {
                    pass = true; Ax = p[1]; Bx = p[2]; Ay = p[3]; By = p[4]; ridx = p[5];
                }
            }
        }
        unsigned long long mask = __ballot(pass);
        if (pass) {
            int slot = __popcll(mask & ((1ull << t) - 1ull));
            float* q = Pc + slot * 6;
            q[0] = wn; q[1] = Ax; q[2] = Bx; q[3] = Ay; q[4] = By; q[5] = ridx;
        }
        if (t == 0) *s_cnt = __popcll(mask);
    }
    __syncthreads();
    const int cnt = *s_cnt;
    const int x = tx0 + (t & 15);
    const int y = ty0 + (t >> 4);
    const float xt = (x + 0.5f) * (1.f / 64.f) - 1.f;
    const float yt = (y + 0.5f) * (1.f / 64.f) - 1.f;
    float a0 = 0.f, a1 = 0.f, a2 = 0.f;
    for (int i = 0; i < cnt; ++i) {
        const float* q = Pc + i * 6;
        float wn = q[0];
        float px = fmaf(xt, q[1], q[2]);
        float py = fmaf(yt, q[3], q[4]);
        if (!(px > -1.f && px < 64.f && py > -1.f && py < 64.f)) continue;
        float x0f = floorf(px), y0f = floorf(py);
        float wx = px - x0f, wy = py - y0f;
        int x0 = (int)x0f, y0 = (int)y0f;
        int x1 = x0 + 1, y1 = y0 + 1;
        bool vx0 = x0 >= 0, vx1 = x1 < 64, vy0 = y0 >= 0, vy1 = y1 < 64;
        int ridx = __float_as_int(q[5]);
        const float* base = dec + (size_t)ridx * NOUT;
        float w00 = (1.f - wx) * (1.f - wy), w10 = wx * (1.f - wy);
        float w01 = (1.f - wx) * wy,         w11 = wx * wy;
        int o00 = y0 * 64 + x0, o10 = y0 * 64 + x1;
        int o01 = y1 * 64 + x0, o11 = y1 * 64 + x1;
        #pragma unroll
        for (int c = 0; c < 3; ++c) {
            const float* cb = base + c * 4096;
            float v00 = (vx0 && vy0) ? cb[o00] : 0.f;
            float v10 = (vx1 && vy0) ? cb[o10] : 0.f;
            float v01 = (vx0 && vy1) ? cb[o01] : 0.f;
            float v11 = (vx1 && vy1) ? cb[o11] : 0.f;
            float sv = v00 * w00 + v10 * w10 + v01 * w01 + v11 * w11;
            if      (c == 0) a0 = fmaf(wn, sv, a0);
            else if (c == 1) a1 = fmaf(wn, sv, a1);
            else             a2 = fmaf(wn, sv, a2);
        }
    }
    out[((size_t)(b * 3 + 0) * IMG + y) * IMG + x] = a0;
    out[((size_t)(b * 3 + 1) * IMG + y) * IMG + x] = a1;
    out[((size_t)(b * 3 + 2) * IMG + y) * IMG + x] = a2;
    __syncthreads();   // Pc reused by next task
}

// ===========================================================================
// Cooperative single-launch kernel (preferred path).
// ===========================================================================
__global__ __launch_bounds__(256, 2) void fused_decoder(
    const float* __restrict__ z_what,  const float* __restrict__ z_where,
    const float* __restrict__ z_depth, const float* __restrict__ w1,
    const float* __restrict__ b1,      const float* __restrict__ w2,
    const float* __restrict__ b2,      const int* __restrict__ z_present,
    const int* __restrict__ indices,
    unsigned short* __restrict__ w2t,  unsigned short* __restrict__ h,
    float* __restrict__ dec,           float* __restrict__ params,
    float* __restrict__ out)
{
    __shared__ char smem[65536];
    cg::grid_group grid = cg::this_grid();
    const int bx = blockIdx.x;
    const int t  = threadIdx.x;

    for (int task = bx; task < 3072; task += CGRID) phaseA_tile(w2, w2t, task, t, smem);
    for (int r    = bx; r    < MPAD; r    += CGRID) phaseB_row(z_what, w1, b1, h, r, t, smem);
    if (bx < B_) phaseC_batch(z_where, z_depth, z_present, indices, params, bx, t);

    __threadfence();   // release: w2t/h/params visible device-wide
    grid.sync();
    __threadfence();   // acquire before cross-XCD reads

    for (int task = bx; task < 288; task += CGRID) phaseD_tile(h, w2t, b2, dec, task, t, smem);

    __threadfence();
    grid.sync();
    __threadfence();

    for (int task = bx; task < 1024; task += CGRID) phaseE_tile(dec, params, out, task, t, smem);
}

// ===========================================================================
// Fallback path: 3 regular launches with identical phase bodies.
// ===========================================================================
__global__ __launch_bounds__(256) void kABC(
    const float* __restrict__ z_what, const float* __restrict__ z_where,
    const float* __restrict__ z_depth, const float* __restrict__ w1,
    const float* __restrict__ b1, const float* __restrict__ w2,
    const int* __restrict__ z_present, const int* __restrict__ indices,
    unsigned short* __restrict__ w2t, unsigned short* __restrict__ h,
    float* __restrict__ params)
{
    __shared__ char smem[16640];
    const int bx = blockIdx.x, t = threadIdx.x;
    if (bx < 3072)      phaseA_tile(w2, w2t, bx, t, smem);
    else if (bx < 3456) phaseB_row(z_what, w1, b1, h, bx - 3072, t, smem);
    else                phaseC_batch(z_where, z_depth, z_present, indices, params, bx - 3456, t);
}

__global__ __launch_bounds__(256) void kD(const unsigned short* __restrict__ h,
                                          const unsigned short* __restrict__ w2t,
                                          const float* __restrict__ b2,
                                          float* __restrict__ dec)
{
    __shared__ char smem[65536];
    phaseD_tile(h, w2t, b2, dec, blockIdx.x, threadIdx.x, smem);
}

__global__ __launch_bounds__(256) void kE(const float* __restrict__ dec,
                                          const float* __restrict__ params,
                                          float* __restrict__ out)
{
    __shared__ char smem[2048];
    phaseE_tile(dec, params, out, blockIdx.x, threadIdx.x, smem);
}

// ---------------------------------------------------------------------------
extern "C" void kernel_launch(void* const* d_in, const int* in_sizes, int n_in,
                              void* d_out, int out_size, void* d_ws, size_t ws_size,
                              hipStream_t stream) {
    const float* z_what    = (const float*)d_in[0];
    const float* z_where   = (const float*)d_in[1];
    const float* z_depth   = (const float*)d_in[2];
    const float* w1        = (const float*)d_in[3];
    const float* b1        = (const float*)d_in[4];
    const float* w2        = (const float*)d_in[5];
    const float* b2        = (const float*)d_in[6];
    const int*   z_present = (const int*)d_in[7];
    const int*   indices   = (const int*)d_in[8];
    float* out = (float*)d_out;

    char* ws = (char*)d_ws;
    unsigned short* w2t = (unsigned short*)ws;                              // 25,165,824 B
    unsigned short* h   = (unsigned short*)(ws + 25165824);                 //    786,432 B
    float*          dec = (float*)(ws + 25165824 + 786432);                 // 18,874,368 B
    float*       params = (float*)(ws + 25165824 + 786432 + 18874368);      //     43,008 B

    void* args[] = {
        (void*)&z_what, (void*)&z_where, (void*)&z_depth, (void*)&w1, (void*)&b1,
        (void*)&w2, (void*)&b2, (void*)&z_present, (void*)&indices,
        (void*)&w2t, (void*)&h, (void*)&dec, (void*)&params, (void*)&out
    };
    hipError_t err = hipLaunchCooperativeKernel((const void*)fused_decoder,
                                                dim3(CGRID), dim3(256),
                                                args, 0, stream);
    if (err != hipSuccess) {
        (void)hipGetLastError();   // clear sticky error; take fallback path
        hipLaunchKernelGGL(kABC, dim3(3472), dim3(256), 0, stream,
                           z_what, z_where, z_depth, w1, b1, w2,
                           z_present, indices, w2t, h, params);
        hipLaunchKernelGGL(kD, dim3(288), dim3(256), 0, stream, h, w2t, b2, dec);
        hipLaunchKernelGGL(kE, dim3(1024), dim3(256), 0, stream, dec, params, out);
    }
}

// Round 8
// 141.776 us; speedup vs baseline: 3.2881x; 3.2881x over previous
//
#include <hip/hip_runtime.h>

#define B_    16
#define NL    21
#define NG    42
#define ZW    64
#define HID   1024
#define IMG   128
#define NOUT  12288   // 3*64*64
#define MROWS 336     // B_*NL
#define MPAD  384

typedef __bf16 bf16x8 __attribute__((ext_vector_type(8)));
typedef float f32x4 __attribute__((ext_vector_type(4)));
typedef unsigned short ushort4v __attribute__((ext_vector_type(4)));

static __device__ __forceinline__ unsigned short f2bf(float f) {
    union { float f; unsigned int u; } v; v.f = f;
    unsigned int r = v.u + 0x7fffu + ((v.u >> 16) & 1u);  // RNE
    return (unsigned short)(r >> 16);
}

// global -> LDS direct copy, 16B per lane (dest must be wave-uniform base + lane*16)
static __device__ __forceinline__ void gload_lds16(const void* g, void* l) {
    __builtin_amdgcn_global_load_lds(
        (const __attribute__((address_space(1))) void*)g,
        (__attribute__((address_space(3))) void*)l,
        16, 0, 0);
}

// ===========================================================================
// Phase bodies (proven correct in R4/R6).
// ===========================================================================

// Phase A: one 64x64 tile of w2 (1024x12288 f32) -> w2t (12288x1024 bf16,
// k-contig, pre-swizzled k ^= (col&7)<<3). task in [0,3072).
static __device__ __forceinline__ void phaseA_tile(const float* __restrict__ w2,
                                                   unsigned short* __restrict__ w2t,
                                                   int task, int t, char* smem) {
    float (*tile)[65] = reinterpret_cast<float (*)[65]>(smem);
    const int nt = task % 192, kt = task / 192;
    const int n0 = nt * 64,    k0 = kt * 64;
    #pragma unroll
    for (int i = 0; i < 4; ++i) {
        int lin = i * 256 + t;
        int kr  = lin >> 4;
        int nc  = (lin & 15) << 2;
        float4 v = *reinterpret_cast<const float4*>(
            w2 + (size_t)(k0 + kr) * NOUT + n0 + nc);
        tile[kr][nc + 0] = v.x; tile[kr][nc + 1] = v.y;
        tile[kr][nc + 2] = v.z; tile[kr][nc + 3] = v.w;
    }
    __syncthreads();
    #pragma unroll
    for (int i = 0; i < 4; ++i) {
        int lin = i * 256 + t;
        int nc  = lin >> 4;
        int kc  = (lin & 15) << 2;
        ushort4v r;
        r.x = f2bf(tile[kc + 0][nc]);
        r.y = f2bf(tile[kc + 1][nc]);
        r.z = f2bf(tile[kc + 2][nc]);
        r.w = f2bf(tile[kc + 3][nc]);
        int kc_s = kc ^ ((nc & 7) << 3);   // pre-swizzle for phase D ds_read
        *reinterpret_cast<ushort4v*>(
            w2t + (size_t)(n0 + nc) * HID + k0 + kc_s) = r;
    }
}

// Phase B: one row r of h = relu(z_what @ w1 + b1) (bf16, pre-swizzled).
static __device__ __forceinline__ void phaseB_row(const float* __restrict__ z_what,
                                                  const float* __restrict__ w1,
                                                  const float* __restrict__ b1,
                                                  unsigned short* __restrict__ h,
                                                  int r, int t, char* smem) {
    const int sw = (r & 7) << 3;
    if (r >= MROWS) {                       // block-uniform branch
        #pragma unroll
        for (int i = 0; i < 4; ++i) {
            int k = t + i * 256;
            h[(size_t)r * HID + ((k & ~63) | ((k & 63) ^ sw))] = 0;
        }
        return;
    }
    float* zs = reinterpret_cast<float*>(smem);
    if (t < ZW) zs[t] = z_what[(size_t)r * ZW + t];
    __syncthreads();
    float acc[4];
    #pragma unroll
    for (int i = 0; i < 4; ++i) acc[i] = b1[t + i * 256];
    for (int k = 0; k < ZW; ++k) {
        float z = zs[k];
        const float* wr = w1 + (size_t)k * HID + t;
        acc[0] = fmaf(z, wr[0],   acc[0]);
        acc[1] = fmaf(z, wr[256], acc[1]);
        acc[2] = fmaf(z, wr[512], acc[2]);
        acc[3] = fmaf(z, wr[768], acc[3]);
    }
    #pragma unroll
    for (int i = 0; i < 4; ++i) {
        int k = t + i * 256;
        h[(size_t)r * HID + ((k & ~63) | ((k & 63) ^ sw))] =
            f2bf(acc[i] > 0.f ? acc[i] : 0.f);
    }
}

// Phase C: batch b softmax weights + affine params + pixel bbox (wave 0 only).
static __device__ __forceinline__ void phaseC_batch(const float* __restrict__ z_where,
                                                    const float* __restrict__ z_depth,
                                                    const int* __restrict__ z_present,
                                                    const int* __restrict__ indices,
                                                    float* __restrict__ params,
                                                    int b, int t) {
    if (t >= 64) return;
    const bool valid = t < NG;
    int idx  = valid ? indices[t] : 0;
    int pres = valid ? z_present[b * NG + t] : 0;
    float zd = z_depth[b * NL + idx];
    const bool on = valid && (pres == 1);
    float val = on ? zd : -__builtin_inff();
    float m = val;
    #pragma unroll
    for (int off = 32; off; off >>= 1) m = fmaxf(m, __shfl_xor(m, off));
    float e = on ? __expf(val - m) : 0.f;
    float s = e;
    #pragma unroll
    for (int off = 32; off; off >>= 1) s += __shfl_xor(s, off);
    if (valid) {
        float wn = e / s;
        const float* zw = z_where + (size_t)(b * NG + t) * 4;
        float cx = zw[0], cy = zw[1], ww = zw[2], hh = zw[3];
        float wm = fmaxf(ww, 1e-6f), hm = fmaxf(hh, 1e-6f);
        float Ax = 32.f / wm, Ay = 32.f / hm;
        float Bx = 31.5f - (2.f * cx - 1.f) * Ax;
        float By = 31.5f - (2.f * cy - 1.f) * Ay;
        float xlof = ((-1.f - Bx) / Ax + 1.f) * 64.f - 0.5f;
        float xhif = (( 64.f - Bx) / Ax + 1.f) * 64.f - 0.5f;
        float ylof = ((-1.f - By) / Ay + 1.f) * 64.f - 0.5f;
        float yhif = (( 64.f - By) / Ay + 1.f) * 64.f - 0.5f;
        int xlo = max(0,   (int)floorf(xlof));
        int xhi = min(128, (int)floorf(xhif) + 2);
        int ylo = max(0,   (int)floorf(ylof));
        int yhi = min(128, (int)floorf(yhif) + 2);
        float* p = params + (size_t)(b * NG + t) * 16;
        p[0] = wn; p[1] = Ax; p[2] = Bx; p[3] = Ay; p[4] = By;
        p[5] = __int_as_float(b * NL + idx);
        p[6] = __int_as_float(xlo); p[7] = __int_as_float(xhi);
        p[8] = __int_as_float(ylo); p[9] = __int_as_float(yhi);
    }
}

// Phase D: one 128x128 tile of dec = sigmoid(h @ w2t^T + b2). task in [0,288).
static __device__ __forceinline__ void phaseD_tile(const unsigned short* __restrict__ h,
                                                   const unsigned short* __restrict__ w2t,
                                                   const float* __restrict__ b2,
                                                   float* __restrict__ dec,
                                                   int task, int t, char* smem) {
    const int bn   = task % 96;
    const int bm   = task / 96;
    const int row0 = bm * 128, col0 = bn * 128;
    const int lane = t & 63, wid = t >> 6;
    const int wr = (wid >> 1) * 64, wc = (wid & 1) * 64;

    f32x4 acc[4][4];
    const f32x4 zero = {0.f, 0.f, 0.f, 0.f};
    #pragma unroll
    for (int m = 0; m < 4; ++m)
        #pragma unroll
        for (int n = 0; n < 4; ++n) acc[m][n] = zero;

    const char* hB = (const char*)h   + ((size_t)row0 << 11);
    const char* wB = (const char*)w2t + ((size_t)col0 << 11);

    #define STAGE(kt_, buf_)                                                    \
        do {                                                                    \
            int kby = (kt_) << 7;                                               \
            char* ldsA = smem + (buf_) * 32768;                                 \
            char* ldsB = ldsA + 16384;                                          \
            _Pragma("unroll")                                                   \
            for (int r_ = 0; r_ < 4; ++r_) {                                    \
                int ci  = r_ * 256 + t;                                         \
                int row = ci >> 3, kc = ci & 7;                                 \
                gload_lds16(hB + ((size_t)row << 11) + kby + (kc << 4),         \
                            ldsA + ci * 16);                                    \
                gload_lds16(wB + ((size_t)row << 11) + kby + (kc << 4),         \
                            ldsB + ci * 16);                                    \
            }                                                                   \
        } while (0)

    #define COMPUTE(buf_)                                                       \
        do {                                                                    \
            const char* Ab = smem + (buf_) * 32768;                             \
            const char* Bb = Ab + 16384;                                        \
            _Pragma("unroll")                                                   \
            for (int ks = 0; ks < 2; ++ks) {                                    \
                int kb = ks * 64 + ((lane >> 4) << 4);                          \
                bf16x8 a[4], bb[4];                                             \
                _Pragma("unroll")                                               \
                for (int m = 0; m < 4; ++m) {                                   \
                    int row = wr + m * 16 + (lane & 15);                        \
                    a[m] = *reinterpret_cast<const bf16x8*>(                    \
                        Ab + row * 128 + (kb ^ ((row & 7) << 4)));              \
                }                                                               \
                _Pragma("unroll")                                               \
                for (int n = 0; n < 4; ++n) {                                   \
                    int col = wc + n * 16 + (lane & 15);                        \
                    bb[n] = *reinterpret_cast<const bf16x8*>(                   \
                        Bb + col * 128 + (kb ^ ((col & 7) << 4)));              \
                }                                                               \
                _Pragma("unroll")                                               \
                for (int m = 0; m < 4; ++m)                                     \
                    _Pragma("unroll")                                           \
                    for (int n = 0; n < 4; ++n)                                 \
                        acc[m][n] = __builtin_amdgcn_mfma_f32_16x16x32_bf16(    \
                            a[m], bb[n], acc[m][n], 0, 0, 0);                   \
            }                                                                   \
        } while (0)

    STAGE(0, 0);
    __syncthreads();
    int cur = 0;
    for (int kt = 1; kt < 16; ++kt) {
        STAGE(kt, cur ^ 1);
        COMPUTE(cur);
        __syncthreads();
        cur ^= 1;
    }
    COMPUTE(cur);
    #undef STAGE
    #undef COMPUTE

    const int rbase = row0 + wr + ((lane >> 4) << 2);
    const int cbase = col0 + wc + (lane & 15);
    #pragma unroll
    for (int n = 0; n < 4; ++n) {
        int col = cbase + n * 16;
        float bias = b2[col];
        #pragma unroll
        for (int m = 0; m < 4; ++m) {
            #pragma unroll
            for (int j = 0; j < 4; ++j) {
                int row = rbase + m * 16 + j;
                float v = acc[m][n][j] + bias;
                dec[(size_t)row * NOUT + col] = 1.f / (1.f + __expf(-v));
            }
        }
    }
}

// Phase E: one 16x16 output tile: glimpse compaction + bilinear + composite.
static __device__ __forceinline__ void phaseE_tile(const float* __restrict__ dec,
                                                   const float* __restrict__ params,
                                                   float* __restrict__ out,
                                                   int task, int t, char* smem) {
    float* Pc    = reinterpret_cast<float*>(smem);              // 42*6 floats
    int*   s_cnt = reinterpret_cast<int*>(smem + NG * 6 * 4);
    const int b    = task >> 6;
    const int tile = task & 63;
    const int tx0 = (tile & 7) << 4, ty0 = (tile >> 3) << 4;
    if (t < 64) {
        bool pass = false;
        float wn = 0.f, Ax = 0.f, Bx = 0.f, Ay = 0.f, By = 0.f, ridx = 0.f;
        if (t < NG) {
            const float* p = params + (size_t)(b * NG + t) * 16;
            wn = p[0];
            if (wn != 0.f) {
                int xlo = __float_as_int(p[6]), xhi = __float_as_int(p[7]);
                int ylo = __float_as_int(p[8]), yhi = __float_as_int(p[9]);
                if (xlo < tx0 + 16 && xhi > tx0 && ylo < ty0 + 16 && yhi > ty0) {
                    pass = true; Ax = p[1]; Bx = p[2]; Ay = p[3]; By = p[4]; ridx = p[5];
                }
            }
        }
        unsigned long long mask = __ballot(pass);
        if (pass) {
            int slot = __popcll(mask & ((1ull << t) - 1ull));
            float* q = Pc + slot * 6;
            q[0] = wn; q[1] = Ax; q[2] = Bx; q[3] = Ay; q[4] = By; q[5] = ridx;
        }
        if (t == 0) *s_cnt = __popcll(mask);
    }
    __syncthreads();
    const int cnt = *s_cnt;
    const int x = tx0 + (t & 15);
    const int y = ty0 + (t >> 4);
    const float xt = (x + 0.5f) * (1.f / 64.f) - 1.f;
    const float yt = (y + 0.5f) * (1.f / 64.f) - 1.f;
    float a0 = 0.f, a1 = 0.f, a2 = 0.f;
    for (int i = 0; i < cnt; ++i) {
        const float* q = Pc + i * 6;
        float wn = q[0];
        float px = fmaf(xt, q[1], q[2]);
        float py = fmaf(yt, q[3], q[4]);
        if (!(px > -1.f && px < 64.f && py > -1.f && py < 64.f)) continue;
        float x0f = floorf(px), y0f = floorf(py);
        float wx = px - x0f, wy = py - y0f;
        int x0 = (int)x0f, y0 = (int)y0f;
        int x1 = x0 + 1, y1 = y0 + 1;
        bool vx0 = x0 >= 0, vx1 = x1 < 64, vy0 = y0 >= 0, vy1 = y1 < 64;
        int ridx = __float_as_int(q[5]);
        const float* base = dec + (size_t)ridx * NOUT;
        float w00 = (1.f - wx) * (1.f - wy), w10 = wx * (1.f - wy);
        float w01 = (1.f - wx) * wy,         w11 = wx * wy;
        int o00 = y0 * 64 + x0, o10 = y0 * 64 + x1;
        int o01 = y1 * 64 + x0, o11 = y1 * 64 + x1;
        #pragma unroll
        for (int c = 0; c < 3; ++c) {
            const float* cb = base + c * 4096;
            float v00 = (vx0 && vy0) ? cb[o00] : 0.f;
            float v10 = (vx1 && vy0) ? cb[o10] : 0.f;
            float v01 = (vx0 && vy1) ? cb[o01] : 0.f;
            float v11 = (vx1 && vy1) ? cb[o11] : 0.f;
            float sv = v00 * w00 + v10 * w10 + v01 * w01 + v11 * w11;
            if      (c == 0) a0 = fmaf(wn, sv, a0);
            else if (c == 1) a1 = fmaf(wn, sv, a1);
            else             a2 = fmaf(wn, sv, a2);
        }
    }
    out[((size_t)(b * 3 + 0) * IMG + y) * IMG + x] = a0;
    out[((size_t)(b * 3 + 1) * IMG + y) * IMG + x] = a1;
    out[((size_t)(b * 3 + 2) * IMG + y) * IMG + x] = a2;
}

// ===========================================================================
// 3-launch structure: kABC (independent pre-work, blockIdx-range dispatch),
// kD (GEMM), kE (composite).
// ===========================================================================
__global__ __launch_bounds__(256) void kABC(
    const float* __restrict__ z_what, const float* __restrict__ z_where,
    const float* __restrict__ z_depth, const float* __restrict__ w1,
    const float* __restrict__ b1, const float* __restrict__ w2,
    const int* __restrict__ z_present, const int* __restrict__ indices,
    unsigned short* __restrict__ w2t, unsigned short* __restrict__ h,
    float* __restrict__ params)
{
    __shared__ char smem[16640];
    const int bx = blockIdx.x, t = threadIdx.x;
    if (bx < 3072)      phaseA_tile(w2, w2t, bx, t, smem);
    else if (bx < 3456) phaseB_row(z_what, w1, b1, h, bx - 3072, t, smem);
    else                phaseC_batch(z_where, z_depth, z_present, indices, params, bx - 3456, t);
}

__global__ __launch_bounds__(256) void kD(const unsigned short* __restrict__ h,
                                          const unsigned short* __restrict__ w2t,
                                          const float* __restrict__ b2,
                                          float* __restrict__ dec)
{
    __shared__ char smem[65536];
    phaseD_tile(h, w2t, b2, dec, blockIdx.x, threadIdx.x, smem);
}

__global__ __launch_bounds__(256) void kE(const float* __restrict__ dec,
                                          const float* __restrict__ params,
                                          float* __restrict__ out)
{
    __shared__ char smem[2048];
    phaseE_tile(dec, params, out, blockIdx.x, threadIdx.x, smem);
}

// ---------------------------------------------------------------------------
extern "C" void kernel_launch(void* const* d_in, const int* in_sizes, int n_in,
                              void* d_out, int out_size, void* d_ws, size_t ws_size,
                              hipStream_t stream) {
    const float* z_what    = (const float*)d_in[0];
    const float* z_where   = (const float*)d_in[1];
    const float* z_depth   = (const float*)d_in[2];
    const float* w1        = (const float*)d_in[3];
    const float* b1        = (const float*)d_in[4];
    const float* w2        = (const float*)d_in[5];
    const float* b2        = (const float*)d_in[6];
    const int*   z_present = (const int*)d_in[7];
    const int*   indices   = (const int*)d_in[8];
    float* out = (float*)d_out;

    char* ws = (char*)d_ws;
    unsigned short* w2t = (unsigned short*)ws;                              // 25,165,824 B
    unsigned short* h   = (unsigned short*)(ws + 25165824);                 //    786,432 B
    float*          dec = (float*)(ws + 25165824 + 786432);                 // 18,874,368 B
    float*       params = (float*)(ws + 25165824 + 786432 + 18874368);      //     43,008 B

    hipLaunchKernelGGL(kABC, dim3(3472), dim3(256), 0, stream,
                       z_what, z_where, z_depth, w1, b1, w2,
                       z_present, indices, w2t, h, params);
    hipLaunchKernelGGL(kD, dim3(288), dim3(256), 0, stream, h, w2t, b2, dec);
    hipLaunchKernelGGL(kE, dim3(1024), dim3(256), 0, stream, dec, params, out);
}